// Round 2
// 291.422 us; speedup vs baseline: 1.0797x; 1.0797x over previous
//
#include <hip/hip_runtime.h>
#include <hip/hip_bf16.h>

// ChebyshevKANLayer: y[b,o] = sum_{i,j} T_j(xhat[b,i]) * C[i,o,j]
// T0==1 folded into fp32 bias; GEMM K = 1024*8 = 8192 (degrees 1..8), bf16 MFMA.
// R8 == R7 with the launch-grid fix (R7 launched 512 blocks for a 256-row tile ->
// OOB fault). GEMM: verified 8-phase/counted-vmcnt template (T3+T4+T5):
//   BM=256 x BN=128, BK=64, 512 thr (8 waves, 4Mx2N), NO split-K.
//   Triple-buffered LDS (3 x 48 KB = 144 KB); s_waitcnt vmcnt(6) counted,
//   never 0 in steady state; setprio(1) around each 16-MFMA cluster.
//   Bijective XCD chunk swizzle: each XCD owns 4 row-panels x all 8 col-blocks.
// ws: bias 4KB | B^T 16.8MB | A 134MB.

typedef __attribute__((ext_vector_type(8))) short bf16x8s;   // MFMA A/B frag (4 VGPRs)
typedef __attribute__((ext_vector_type(4))) float f32x4;     // MFMA C/D frag

constexpr int BROWS = 8192;
constexpr int IDIM  = 1024;
constexpr int ODIM  = 1024;
constexpr int DEG1  = 9;
constexpr int KP    = 8;             // stored degrees 1..8 per input i
constexpr int KD    = IDIM * KP;     // 8192

__device__ __forceinline__ ushort f2bf(float f) {
  return ((__hip_bfloat16_raw)__float2bfloat16(f)).x;
}

// async global->LDS, 16 B per lane. LDS dst MUST be wave-uniform base + lane*16.
__device__ __forceinline__ void gload_lds16(const void* g, void* l) {
  __builtin_amdgcn_global_load_lds(
      (const __attribute__((address_space(1))) unsigned int*)g,
      (__attribute__((address_space(3))) unsigned int*)l, 16, 0, 0);
}

// ---------- 0. zero the bias accumulator (ws is poisoned every call) ----------
__global__ __launch_bounds__(256) void zero_bias_kernel(float* __restrict__ bias) {
  bias[blockIdx.x * 256 + threadIdx.x] = 0.0f;
}

// ---------- 1. fused rowstats + A-build: A[b][i*8+d'] = T_{d'+1}(xhat) bf16 ----------
__global__ __launch_bounds__(256) void build_a_kernel(const float* __restrict__ x,
                                                      ushort* __restrict__ A2) {
  __shared__ float red[8];
  const int b = blockIdx.x, t = threadIdx.x, lane = t & 63, wv = t >> 6;
  const float* xr = x + (size_t)b * IDIM;
  const float4 v = ((const float4*)xr)[t];                 // i = 4t..4t+3
  float mn = fminf(fminf(v.x, v.y), fminf(v.z, v.w));
  float mx = fmaxf(fmaxf(v.x, v.y), fmaxf(v.z, v.w));
#pragma unroll
  for (int off = 32; off >= 1; off >>= 1) {
    mn = fminf(mn, __shfl_xor(mn, off));
    mx = fmaxf(mx, __shfl_xor(mx, off));
  }
  if (lane == 0) { red[wv] = mn; red[4 + wv] = mx; }
  __syncthreads();
  mn = fminf(fminf(red[0], red[1]), fminf(red[2], red[3]));
  mx = fmaxf(fmaxf(red[4], red[5]), fmaxf(red[6], red[7]));
  const float sc = 2.0f / (mx - mn);
  const float of = -mn * sc - 1.0f;

  uint4* adst = (uint4*)(A2 + (size_t)b * KD);
#pragma unroll
  for (int c = 0; c < 4; ++c) {
    const int i = c * 256 + t;                             // lanes consecutive
    const float xn = fmaf(sc, xr[i], of);                  // L1-hot re-read
    const float T2 = 2.f * xn * xn - 1.f;
    const float T3 = 2.f * xn * T2 - xn;
    const float T4 = 2.f * xn * T3 - T2;
    const float T5 = 2.f * xn * T4 - T3;
    const float T6 = 2.f * xn * T5 - T4;
    const float T7 = 2.f * xn * T6 - T5;
    const float T8 = 2.f * xn * T7 - T6;
    uint4 w;
    w.x = (uint)f2bf(xn) | ((uint)f2bf(T2) << 16);         // d' 0,1 = T1,T2
    w.y = (uint)f2bf(T3) | ((uint)f2bf(T4) << 16);
    w.z = (uint)f2bf(T5) | ((uint)f2bf(T6) << 16);
    w.w = (uint)f2bf(T7) | ((uint)f2bf(T8) << 16);
    adst[i] = w;                                           // coalesced 16 B/lane
  }
}

// ---------- 2. B^T[o][i*8+d'] = C[i][o][d'+1] bf16; j==0 -> fp32 bias ----------
__global__ __launch_bounds__(256) void build_b_kernel(const float* __restrict__ coeffs,
                                                      ushort* __restrict__ B2T,
                                                      float* __restrict__ bias) {
  __shared__ __align__(16) ushort tile[64 * 256];          // 32 KB [o_l][i_l*8+d']
  __shared__ float lb[64];
  const int i0 = blockIdx.x * 32;
  const int o0 = blockIdx.y * 64;
  const int t  = threadIdx.x;
  if (t < 64) lb[t] = 0.0f;
  __syncthreads();
  for (int idx = t; idx < 18432; idx += 256) {             // coalesced float reads
    const int i_l = idx / 576;                             // 576 = 64*9
    const int rem = idx - i_l * 576;                       // = o_l*9 + j
    const float v = coeffs[((size_t)(i0 + i_l) * ODIM + o0) * DEG1 + rem];
    const int o_l = rem / 9;
    const int j   = rem - o_l * 9;
    if (j == 0) atomicAdd(&lb[o_l], v);                    // exact fp32 bias path
    else tile[o_l * 256 + i_l * KP + (j - 1)] = f2bf(v);
  }
  __syncthreads();
  for (int idx = t; idx < 2048; idx += 256) {              // coalesced uint4 writes
    const int o_l = idx >> 5;
    const int w   = idx & 31;
    uint4* gdst = (uint4*)(B2T + (size_t)(o0 + o_l) * KD + i0 * KP);
    gdst[w] = ((const uint4*)tile)[idx];
  }
  if (t < 64) atomicAdd(&bias[o0 + t], lb[t]);             // device-scope fp32 add
}

// ---------- 3. GEMM: 256x128 tile, BK=64, 3-deep pipeline, counted vmcnt ----------
// Phase = {8 x ds_read_b128 | 3 x global_load_lds issue} ; s_barrier ;
//         lgkmcnt(0) ; setprio(1) ; 16 MFMA ; setprio(0) ; [vmcnt(6)] ; s_barrier.
// Per wave per K-tile: 2 phases (kh=0/1). Tile it+2 is staged into the buffer
// that held tile it-1 (3 buffers); vmcnt(6) at end of each tile completes tile
// it+1 while tile it+2's 6 loads stay in flight across barriers.
#define GEMM_PHASE(CX, ISSUE_STMT, TAILWAIT_STMT)                                 \
  {                                                                               \
    bf16x8s afr[4], bfr[4];                                                       \
    _Pragma("unroll")                                                             \
    for (int m = 0; m < 4; ++m)                                                   \
      afr[m] = *(const bf16x8s*)&Asb[aoff + m * (16 * 64) + (CX)];                \
    _Pragma("unroll")                                                             \
    for (int n = 0; n < 4; ++n)                                                   \
      bfr[n] = *(const bf16x8s*)&Bsb[boff + n * (16 * 64) + (CX)];                \
    ISSUE_STMT;                                                                   \
    __builtin_amdgcn_s_barrier();                                                 \
    asm volatile("s_waitcnt lgkmcnt(0)" ::: "memory");                            \
    __builtin_amdgcn_s_setprio(1);                                                \
    _Pragma("unroll")                                                             \
    for (int m = 0; m < 4; ++m)                                                   \
      _Pragma("unroll")                                                           \
      for (int n = 0; n < 4; ++n)                                                 \
        acc[m][n] = __builtin_amdgcn_mfma_f32_16x16x32_bf16(afr[m], bfr[n],       \
                                                            acc[m][n], 0, 0, 0);  \
    __builtin_amdgcn_s_setprio(0);                                                \
    TAILWAIT_STMT;                                                                \
    __builtin_amdgcn_s_barrier();                                                 \
  }

__global__ __launch_bounds__(512, 2) void gemm_kernel(const ushort* __restrict__ A2,
                                                      const ushort* __restrict__ B2T,
                                                      const float* __restrict__ bias,
                                                      float* __restrict__ out) {
  constexpr int BK    = 64;
  constexpr int KT    = KD / BK;       // 128 K-tiles
  constexpr int ABUF  = 256 * BK;      // 16384 ushorts = 32 KB
  constexpr int BBUF  = 128 * BK;      //  8192 ushorts = 16 KB
  constexpr int BUFSZ = ABUF + BBUF;   // 24576 ushorts = 48 KB
  __shared__ __align__(16) ushort Sm[3 * BUFSZ];   // 144 KB -> 1 block/CU

  const int t    = threadIdx.x;
  const int lane = t & 63;
  const int wave = t >> 6;
  const int wr   = wave >> 1;          // 0..3 : M sub-block (64 rows each)
  const int wc   = wave & 1;           // 0..1 : N sub-block (64 cols each)
  const int c16  = lane & 15;
  const int quad = lane >> 4;

  // bijective XCD chunk swizzle (256 wgs % 8 == 0): XCD k -> rows 4k..4k+3, all cols
  const int orig = blockIdx.y * 8 + blockIdx.x;    // grid (8, 32), x = col fastest
  const int swz  = (orig & 7) * 32 + (orig >> 3);
  const int rowBase = (swz >> 3) * 256;
  const int colBase = (swz & 7) * 128;

  // staging: thread t covers row trow (+64 per issue), 16B chunk t&7;
  // global col chunk XOR-permuted so the lane-linear LDS dst realizes the swizzle.
  const int trow = t >> 3;                         // 0..63
  const int scol = (t & 7) ^ (trow & 7);
  const ushort* aB = A2  + (size_t)(rowBase + trow) * KD + scol * 8;
  const ushort* bB = B2T + (size_t)(colBase + trow) * KD + scol * 8;
  ushort* uA = Sm + t * 8;                         // wave-uniform base + lane*16B
  ushort* uB = Sm + ABUF + t * 8;

  auto issA = [&](int buf, size_t ko, int a) {
    gload_lds16(aB + (size_t)a * (64 * KD) + ko, uA + buf * BUFSZ + a * 4096);
  };
  auto issB = [&](int buf, size_t ko, int b2) {
    gload_lds16(bB + (size_t)b2 * (64 * KD) + ko, uB + buf * BUFSZ + b2 * 4096);
  };

  // per-wave LDS read offsets (ushort idx); swizzled col-chunk for kh=0/1
  const int aoff = (wr * 64 + c16) * BK;
  const int boff = (wc * 64 + c16) * BK;
  const int cx0  = ((0 + quad) ^ (c16 & 7)) * 8;
  const int cx1  = ((4 + quad) ^ (c16 & 7)) * 8;

  f32x4 acc[4][4];
#pragma unroll
  for (int m = 0; m < 4; ++m)
#pragma unroll
    for (int n = 0; n < 4; ++n) acc[m][n] = (f32x4){0.f, 0.f, 0.f, 0.f};

  // prologue: stage tiles 0,1 -> bufs 0,1 ; complete tile 0 (6 left in flight)
  issA(0, 0, 0); issA(0, 0, 1); issA(0, 0, 2); issA(0, 0, 3);
  issB(0, 0, 0); issB(0, 0, 1);
  issA(1, BK, 0); issA(1, BK, 1); issA(1, BK, 2); issA(1, BK, 3);
  issB(1, BK, 0); issB(1, BK, 1);
  asm volatile("s_waitcnt vmcnt(6)" ::: "memory");
  __builtin_amdgcn_s_barrier();

  int cur = 0;
  for (int it = 0; it < KT; ++it) {
    const ushort* Asb = Sm + cur * BUFSZ;
    const ushort* Bsb = Asb + ABUF;
    const int nb = (cur >= 1) ? cur - 1 : 2;       // (cur+2)%3: held tile it-1
    const size_t ko = (size_t)(it + 2) * BK;
    const bool pf = (it < KT - 2);

    GEMM_PHASE(cx0,
      if (pf) { issA(nb, ko, 0); issA(nb, ko, 1); issA(nb, ko, 2); },
      ;);
    GEMM_PHASE(cx1,
      if (pf) { issA(nb, ko, 3); issB(nb, ko, 0); issB(nb, ko, 1); },
      if (pf)              { asm volatile("s_waitcnt vmcnt(6)" ::: "memory"); }
      else if (it == KT-2) { asm volatile("s_waitcnt vmcnt(0)" ::: "memory"); });

    cur = (cur == 2) ? 0 : cur + 1;
  }

  // ---- epilogue: straight from registers (no split-K), add bias ----
#pragma unroll
  for (int n = 0; n < 4; ++n) {
    const int col = colBase + wc * 64 + n * 16 + c16;
    const float bv = bias[col];
#pragma unroll
    for (int m = 0; m < 4; ++m) {
      const int r0 = rowBase + wr * 64 + m * 16 + quad * 4;
#pragma unroll
      for (int r = 0; r < 4; ++r)
        out[(size_t)(r0 + r) * ODIM + col] = acc[m][n][r] + bv;
    }
  }
}

extern "C" void kernel_launch(void* const* d_in, const int* in_sizes, int n_in,
                              void* d_out, int out_size, void* d_ws, size_t ws_size,
                              hipStream_t stream) {
  const float* x      = (const float*)d_in[0];   // [8192,1024] fp32
  const float* coeffs = (const float*)d_in[1];   // [1024,1024,9] fp32
  float* out = (float*)d_out;                    // [8192,1024] fp32

  char* ws = (char*)d_ws;
  float*  bias = (float*)ws;                                        // 4 KB (pad 64K)
  ushort* B2T  = (ushort*)(ws + 65536);                             // 16.78 MB
  ushort* A2   = (ushort*)(ws + 65536 + (size_t)ODIM * KD * 2);     // 134.2 MB
  // total ws: ~151 MB

  zero_bias_kernel<<<ODIM / 256, 256, 0, stream>>>(bias);
  build_a_kernel<<<BROWS, 256, 0, stream>>>(x, A2);
  build_b_kernel<<<dim3(IDIM / 32, ODIM / 64), 256, 0, stream>>>(coeffs, B2T, bias);
  // 256x128 tile -> grid (ODIM/128, BROWS/256) = (8, 32) = 256 blocks (R7 bug: /128)
  gemm_kernel<<<dim3(ODIM / 128, BROWS / 256), 512, 0, stream>>>(A2, B2T, bias, out);
}

// Round 3
// 275.784 us; speedup vs baseline: 1.1409x; 1.0567x over previous
//
#include <hip/hip_runtime.h>
#include <hip/hip_bf16.h>

// ChebyshevKANLayer: y[b,o] = sum_{i,j} T_j(xhat[b,i]) * C[i,o,j]
// T0==1 folded into fp32 bias; GEMM K = 1024*8 = 8192 (degrees 1..8), bf16 MFMA.
// R9: single-barrier K-tile. R8 measured MfmaUtil 43%, bank-conflict 0, HBM
// irrelevant (warm replays: 35MB fetch, same 139us) -> stall is sync: 4 barriers
// + 2 lgkmcnt(0) drains per K-tile. Triple buffering makes the pre-MFMA barrier
// and full lgkm drain unnecessary: reads hit buf cur, staging hits buf nb
// (consumed before the PREVIOUS end-of-tile barrier). Keep: counted vmcnt(6),
// setprio around MFMA clusters, XOR-swizzled LDS, XCD chunk swizzle.
//   BM=256 x BN=128, BK=64, 512 thr (8 waves, 4Mx2N), 3 x 48KB LDS.
// ws: bias 4KB | B^T 16.8MB | A 134MB.

typedef __attribute__((ext_vector_type(8))) short bf16x8s;   // MFMA A/B frag (4 VGPRs)
typedef __attribute__((ext_vector_type(4))) float f32x4;     // MFMA C/D frag

constexpr int BROWS = 8192;
constexpr int IDIM  = 1024;
constexpr int ODIM  = 1024;
constexpr int DEG1  = 9;
constexpr int KP    = 8;             // stored degrees 1..8 per input i
constexpr int KD    = IDIM * KP;     // 8192

__device__ __forceinline__ ushort f2bf(float f) {
  return ((__hip_bfloat16_raw)__float2bfloat16(f)).x;
}

// async global->LDS, 16 B per lane. LDS dst MUST be wave-uniform base + lane*16.
__device__ __forceinline__ void gload_lds16(const void* g, void* l) {
  __builtin_amdgcn_global_load_lds(
      (const __attribute__((address_space(1))) unsigned int*)g,
      (__attribute__((address_space(3))) unsigned int*)l, 16, 0, 0);
}

// ---------- 0. zero the bias accumulator (ws is poisoned every call) ----------
__global__ __launch_bounds__(256) void zero_bias_kernel(float* __restrict__ bias) {
  bias[blockIdx.x * 256 + threadIdx.x] = 0.0f;
}

// ---------- 1. fused rowstats + A-build: A[b][i*8+d'] = T_{d'+1}(xhat) bf16 ----------
__global__ __launch_bounds__(256) void build_a_kernel(const float* __restrict__ x,
                                                      ushort* __restrict__ A2) {
  __shared__ float red[8];
  const int b = blockIdx.x, t = threadIdx.x, lane = t & 63, wv = t >> 6;
  const float* xr = x + (size_t)b * IDIM;
  const float4 v = ((const float4*)xr)[t];                 // i = 4t..4t+3
  float mn = fminf(fminf(v.x, v.y), fminf(v.z, v.w));
  float mx = fmaxf(fmaxf(v.x, v.y), fmaxf(v.z, v.w));
#pragma unroll
  for (int off = 32; off >= 1; off >>= 1) {
    mn = fminf(mn, __shfl_xor(mn, off));
    mx = fmaxf(mx, __shfl_xor(mx, off));
  }
  if (lane == 0) { red[wv] = mn; red[4 + wv] = mx; }
  __syncthreads();
  mn = fminf(fminf(red[0], red[1]), fminf(red[2], red[3]));
  mx = fmaxf(fmaxf(red[4], red[5]), fmaxf(red[6], red[7]));
  const float sc = 2.0f / (mx - mn);
  const float of = -mn * sc - 1.0f;

  uint4* adst = (uint4*)(A2 + (size_t)b * KD);
#pragma unroll
  for (int c = 0; c < 4; ++c) {
    const int i = c * 256 + t;                             // lanes consecutive
    const float xn = fmaf(sc, xr[i], of);                  // L1-hot re-read
    const float T2 = 2.f * xn * xn - 1.f;
    const float T3 = 2.f * xn * T2 - xn;
    const float T4 = 2.f * xn * T3 - T2;
    const float T5 = 2.f * xn * T4 - T3;
    const float T6 = 2.f * xn * T5 - T4;
    const float T7 = 2.f * xn * T6 - T5;
    const float T8 = 2.f * xn * T7 - T6;
    uint4 w;
    w.x = (uint)f2bf(xn) | ((uint)f2bf(T2) << 16);         // d' 0,1 = T1,T2
    w.y = (uint)f2bf(T3) | ((uint)f2bf(T4) << 16);
    w.z = (uint)f2bf(T5) | ((uint)f2bf(T6) << 16);
    w.w = (uint)f2bf(T7) | ((uint)f2bf(T8) << 16);
    adst[i] = w;                                           // coalesced 16 B/lane
  }
}

// ---------- 2. B^T[o][i*8+d'] = C[i][o][d'+1] bf16; j==0 -> fp32 bias ----------
__global__ __launch_bounds__(256) void build_b_kernel(const float* __restrict__ coeffs,
                                                      ushort* __restrict__ B2T,
                                                      float* __restrict__ bias) {
  __shared__ __align__(16) ushort tile[64 * 256];          // 32 KB [o_l][i_l*8+d']
  __shared__ float lb[64];
  const int i0 = blockIdx.x * 32;
  const int o0 = blockIdx.y * 64;
  const int t  = threadIdx.x;
  if (t < 64) lb[t] = 0.0f;
  __syncthreads();
  for (int idx = t; idx < 18432; idx += 256) {             // coalesced float reads
    const int i_l = idx / 576;                             // 576 = 64*9
    const int rem = idx - i_l * 576;                       // = o_l*9 + j
    const float v = coeffs[((size_t)(i0 + i_l) * ODIM + o0) * DEG1 + rem];
    const int o_l = rem / 9;
    const int j   = rem - o_l * 9;
    if (j == 0) atomicAdd(&lb[o_l], v);                    // exact fp32 bias path
    else tile[o_l * 256 + i_l * KP + (j - 1)] = f2bf(v);
  }
  __syncthreads();
  for (int idx = t; idx < 2048; idx += 256) {              // coalesced uint4 writes
    const int o_l = idx >> 5;
    const int w   = idx & 31;
    uint4* gdst = (uint4*)(B2T + (size_t)(o0 + o_l) * KD + i0 * KP);
    gdst[w] = ((const uint4*)tile)[idx];
  }
  if (t < 64) atomicAdd(&bias[o0 + t], lb[t]);             // device-scope fp32 add
}

// ---------- 3. GEMM: 256x128 tile, BK=64, 3-deep pipeline, ONE barrier/tile ----
// Per K-tile: {8 ds_read | issue 3 gloads | 16 MFMA} x2 ; vmcnt(6) ; s_barrier.
// Compiler emits its own fine-grained lgkmcnt(N) for the frag loads; with no
// mid-tile barrier it can software-pipeline phase1 reads under phase0 MFMAs.
// Buffer hazards: reads hit cur (completed by prev tile's vmcnt(6)+barrier);
// staging hits nb = tile it-1's buffer (all reads of it done before the
// end-of-tile-(it-1) barrier). One barrier per tile is sufficient.
__global__ __launch_bounds__(512, 1) void gemm_kernel(const ushort* __restrict__ A2,
                                                      const ushort* __restrict__ B2T,
                                                      const float* __restrict__ bias,
                                                      float* __restrict__ out) {
  constexpr int BK    = 64;
  constexpr int KT    = KD / BK;       // 128 K-tiles
  constexpr int ABUF  = 256 * BK;      // 16384 ushorts = 32 KB
  constexpr int BBUF  = 128 * BK;      //  8192 ushorts = 16 KB
  constexpr int BUFSZ = ABUF + BBUF;   // 24576 ushorts = 48 KB
  __shared__ __align__(16) ushort Sm[3 * BUFSZ];   // 144 KB -> 1 block/CU

  const int t    = threadIdx.x;
  const int lane = t & 63;
  const int wave = t >> 6;
  const int wr   = wave >> 1;          // 0..3 : M sub-block (64 rows each)
  const int wc   = wave & 1;           // 0..1 : N sub-block (64 cols each)
  const int c16  = lane & 15;
  const int quad = lane >> 4;

  // bijective XCD chunk swizzle (256 wgs % 8 == 0): XCD k -> rows 4k..4k+3, all cols
  const int orig = blockIdx.y * 8 + blockIdx.x;    // grid (8, 32), x = col fastest
  const int swz  = (orig & 7) * 32 + (orig >> 3);
  const int rowBase = (swz >> 3) * 256;
  const int colBase = (swz & 7) * 128;

  // staging: thread t covers row trow (+64 per issue), 16B chunk t&7;
  // global col chunk XOR-permuted so the lane-linear LDS dst realizes the swizzle.
  const int trow = t >> 3;                         // 0..63
  const int scol = (t & 7) ^ (trow & 7);
  const ushort* aB = A2  + (size_t)(rowBase + trow) * KD + scol * 8;
  const ushort* bB = B2T + (size_t)(colBase + trow) * KD + scol * 8;
  ushort* uA = Sm + t * 8;                         // wave-uniform base + lane*16B
  ushort* uB = Sm + ABUF + t * 8;

  auto issA = [&](int buf, size_t ko, int a) {
    gload_lds16(aB + (size_t)a * (64 * KD) + ko, uA + buf * BUFSZ + a * 4096);
  };
  auto issB = [&](int buf, size_t ko, int b2) {
    gload_lds16(bB + (size_t)b2 * (64 * KD) + ko, uB + buf * BUFSZ + b2 * 4096);
  };

  // per-wave LDS read offsets (ushort idx); swizzled col-chunk for kh=0/1
  const int aoff = (wr * 64 + c16) * BK;
  const int boff = (wc * 64 + c16) * BK;
  const int cx0  = ((0 + quad) ^ (c16 & 7)) * 8;
  const int cx1  = ((4 + quad) ^ (c16 & 7)) * 8;

  f32x4 acc[4][4];
#pragma unroll
  for (int m = 0; m < 4; ++m)
#pragma unroll
    for (int n = 0; n < 4; ++n) acc[m][n] = (f32x4){0.f, 0.f, 0.f, 0.f};

  // prologue: stage tiles 0,1 -> bufs 0,1 ; complete tile 0 (6 left in flight)
  issA(0, 0, 0); issA(0, 0, 1); issA(0, 0, 2); issA(0, 0, 3);
  issB(0, 0, 0); issB(0, 0, 1);
  issA(1, BK, 0); issA(1, BK, 1); issA(1, BK, 2); issA(1, BK, 3);
  issB(1, BK, 0); issB(1, BK, 1);
  asm volatile("s_waitcnt vmcnt(6)" ::: "memory");
  __builtin_amdgcn_s_barrier();

  int cur = 0;
  for (int it = 0; it < KT; ++it) {
    const ushort* Asb = Sm + cur * BUFSZ;
    const ushort* Bsb = Asb + ABUF;
    const int nb = (cur >= 1) ? cur - 1 : 2;       // (cur+2)%3: held tile it-1
    const size_t ko = (size_t)(it + 2) * BK;
    const bool pf = (it < KT - 2);

    {                                              // ---- phase 0 (k 0..31) ----
      bf16x8s afr[4], bfr[4];
#pragma unroll
      for (int m = 0; m < 4; ++m)
        afr[m] = *(const bf16x8s*)&Asb[aoff + m * (16 * 64) + cx0];
#pragma unroll
      for (int n = 0; n < 4; ++n)
        bfr[n] = *(const bf16x8s*)&Bsb[boff + n * (16 * 64) + cx0];
      if (pf) { issA(nb, ko, 0); issA(nb, ko, 1); issA(nb, ko, 2); }
      __builtin_amdgcn_s_setprio(1);
#pragma unroll
      for (int m = 0; m < 4; ++m)
#pragma unroll
        for (int n = 0; n < 4; ++n)
          acc[m][n] = __builtin_amdgcn_mfma_f32_16x16x32_bf16(afr[m], bfr[n],
                                                              acc[m][n], 0, 0, 0);
      __builtin_amdgcn_s_setprio(0);
    }
    {                                              // ---- phase 1 (k 32..63) ----
      bf16x8s afr[4], bfr[4];
#pragma unroll
      for (int m = 0; m < 4; ++m)
        afr[m] = *(const bf16x8s*)&Asb[aoff + m * (16 * 64) + cx1];
#pragma unroll
      for (int n = 0; n < 4; ++n)
        bfr[n] = *(const bf16x8s*)&Bsb[boff + n * (16 * 64) + cx1];
      if (pf) { issA(nb, ko, 3); issB(nb, ko, 0); issB(nb, ko, 1); }
      __builtin_amdgcn_s_setprio(1);
#pragma unroll
      for (int m = 0; m < 4; ++m)
#pragma unroll
        for (int n = 0; n < 4; ++n)
          acc[m][n] = __builtin_amdgcn_mfma_f32_16x16x32_bf16(afr[m], bfr[n],
                                                              acc[m][n], 0, 0, 0);
      __builtin_amdgcn_s_setprio(0);
    }

    if (pf)              { asm volatile("s_waitcnt vmcnt(6)" ::: "memory"); }
    else if (it == KT-2) { asm volatile("s_waitcnt vmcnt(0)" ::: "memory"); }
    __builtin_amdgcn_s_barrier();                  // ONE barrier per K-tile

    cur = (cur == 2) ? 0 : cur + 1;
  }

  // ---- epilogue: straight from registers (no split-K), add bias ----
#pragma unroll
  for (int n = 0; n < 4; ++n) {
    const int col = colBase + wc * 64 + n * 16 + c16;
    const float bv = bias[col];
#pragma unroll
    for (int m = 0; m < 4; ++m) {
      const int r0 = rowBase + wr * 64 + m * 16 + quad * 4;
#pragma unroll
      for (int r = 0; r < 4; ++r)
        out[(size_t)(r0 + r) * ODIM + col] = acc[m][n][r] + bv;
    }
  }
}

extern "C" void kernel_launch(void* const* d_in, const int* in_sizes, int n_in,
                              void* d_out, int out_size, void* d_ws, size_t ws_size,
                              hipStream_t stream) {
  const float* x      = (const float*)d_in[0];   // [8192,1024] fp32
  const float* coeffs = (const float*)d_in[1];   // [1024,1024,9] fp32
  float* out = (float*)d_out;                    // [8192,1024] fp32

  char* ws = (char*)d_ws;
  float*  bias = (float*)ws;                                        // 4 KB (pad 64K)
  ushort* B2T  = (ushort*)(ws + 65536);                             // 16.78 MB
  ushort* A2   = (ushort*)(ws + 65536 + (size_t)ODIM * KD * 2);     // 134.2 MB
  // total ws: ~151 MB

  zero_bias_kernel<<<ODIM / 256, 256, 0, stream>>>(bias);
  build_a_kernel<<<BROWS, 256, 0, stream>>>(x, A2);
  build_b_kernel<<<dim3(IDIM / 32, ODIM / 64), 256, 0, stream>>>(coeffs, B2T, bias);
  // 256x128 tile -> grid (ODIM/128, BROWS/256) = (8, 32) = 256 blocks
  gemm_kernel<<<dim3(ODIM / 128, BROWS / 256), 512, 0, stream>>>(A2, B2T, bias, out);
}